// Round 1
// baseline (193.097 us; speedup 1.0000x reference)
//
#include <hip/hip_runtime.h>

// Problem constants (from reference setup_inputs)
#define BB 4096   // batch
#define SS 256    // sequence length
#define FF 64     // features
#define GG 9      // 3*U gate width
#define GP 12     // padded gate width for float4 alignment

#if __has_builtin(__builtin_amdgcn_exp2f)
__device__ __forceinline__ float fast_exp2(float x) { return __builtin_amdgcn_exp2f(x); }
#else
__device__ __forceinline__ float fast_exp2(float x) { return exp2f(x); }
#endif
#if __has_builtin(__builtin_amdgcn_rcpf)
__device__ __forceinline__ float fast_rcp(float x) { return __builtin_amdgcn_rcpf(x); }
#else
__device__ __forceinline__ float fast_rcp(float x) { return 1.0f / x; }
#endif

__device__ __forceinline__ float sigmoid_f(float x) {
  // 1/(1+exp(-x)) = 1/(1+exp2(-x*log2e))
  return fast_rcp(1.0f + fast_exp2(-1.4426950408889634f * x));
}
__device__ __forceinline__ float tanh_f(float x) {
  // tanh(x) = 1 - 2/(exp2(2x*log2e)+1); saturates correctly at +-inf
  return 1.0f - 2.0f * fast_rcp(1.0f + fast_exp2(2.8853900817779268f * x));
}

// Phase 1: xk[s][b][0..8] = x[b,s,:] @ kernel + bias[0]
// One wave handles 4 rows (same s, consecutive b), 16 lanes per row,
// 4 features per lane, butterfly-reduce over the 16-lane group.
__global__ __launch_bounds__(256) void proj_kernel(
    const float* __restrict__ x,       // [B,S,F]
    const float* __restrict__ kernel,  // [F,9]
    const float* __restrict__ bias,    // [2,9]
    float* __restrict__ xk)            // [S,B,12]
{
  const int lane = threadIdx.x & 63;
  const int wave = threadIdx.x >> 6;
  const int sub  = lane & 15;  // feature-chunk id within row group
  const int rg   = lane >> 4;  // row (batch) within wave

  // kernel slice for features 4*sub .. 4*sub+3 -> registers (36 VGPRs)
  float kk[4][GG];
#pragma unroll
  for (int f = 0; f < 4; ++f)
#pragma unroll
    for (int g = 0; g < GG; ++g)
      kk[f][g] = kernel[(4 * sub + f) * GG + g];

  float b0[GG];
#pragma unroll
  for (int g = 0; g < GG; ++g) b0[g] = bias[g];

  const int s = blockIdx.y;             // time step
  const int bbase = blockIdx.x * 64;    // 64 batches per block (4 iters x 16)

#pragma unroll 2
  for (int it = 0; it < 4; ++it) {
    const int b = bbase + it * 16 + wave * 4 + rg;
    const float4 xv = *reinterpret_cast<const float4*>(
        x + ((size_t)b * SS + s) * FF + sub * 4);
    float a[GG];
#pragma unroll
    for (int g = 0; g < GG; ++g)
      a[g] = xv.x * kk[0][g] + xv.y * kk[1][g] + xv.z * kk[2][g] + xv.w * kk[3][g];
    // butterfly reduce over the 16-lane row group (masks 1,2,4,8 stay in-group)
#pragma unroll
    for (int off = 1; off < 16; off <<= 1)
#pragma unroll
      for (int g = 0; g < GG; ++g)
        a[g] += __shfl_xor(a[g], off, 64);

    if (sub == 0) {
      float* o = xk + ((size_t)s * BB + b) * GP;
      float4 w0 = make_float4(a[0] + b0[0], a[1] + b0[1], a[2] + b0[2], a[3] + b0[3]);
      float4 w1 = make_float4(a[4] + b0[4], a[5] + b0[5], a[6] + b0[6], a[7] + b0[7]);
      float4 w2 = make_float4(a[8] + b0[8], 0.0f, 0.0f, 0.0f);
      *reinterpret_cast<float4*>(o)     = w0;
      *reinterpret_cast<float4*>(o + 4) = w1;
      *reinterpret_cast<float4*>(o + 8) = w2;
    }
  }
}

// Phase 2: per-batch sequential GRU scan + dense + softmax.
// One thread per batch element (4096 threads total).
__global__ __launch_bounds__(64) void gru_kernel(
    const float* __restrict__ xk,          // [S,B,12]
    const float* __restrict__ rec_kernel,  // [3,9]
    const float* __restrict__ bias,        // [2,9]
    const float* __restrict__ dense_w,     // [3,10]
    const float* __restrict__ dense_b,     // [10]
    float* __restrict__ out)               // [B,10]
{
  const int b = blockIdx.x * 64 + threadIdx.x;

  float rk[3][GG];
#pragma unroll
  for (int u = 0; u < 3; ++u)
#pragma unroll
    for (int g = 0; g < GG; ++g)
      rk[u][g] = rec_kernel[u * GG + g];
  float rb[GG];
#pragma unroll
  for (int g = 0; g < GG; ++g) rb[g] = bias[GG + g];

  float h0 = 0.0f, h1 = 0.0f, h2 = 0.0f;

  // software prefetch of step 0
  const float* p0 = xk + (size_t)b * GP;
  float4 v0 = *reinterpret_cast<const float4*>(p0);
  float4 v1 = *reinterpret_cast<const float4*>(p0 + 4);
  float4 v2 = *reinterpret_cast<const float4*>(p0 + 8);

  for (int s = 0; s < SS; ++s) {
    // prefetch next step (clamped harmless reload on last iter)
    const int sn = (s + 1 < SS) ? s + 1 : SS - 1;
    const float* pn = xk + ((size_t)sn * BB + b) * GP;
    const float4 n0 = *reinterpret_cast<const float4*>(pn);
    const float4 n1 = *reinterpret_cast<const float4*>(pn + 4);
    const float4 n2 = *reinterpret_cast<const float4*>(pn + 8);

    float inner[GG];
#pragma unroll
    for (int g = 0; g < GG; ++g)
      inner[g] = rb[g] + h0 * rk[0][g] + h1 * rk[1][g] + h2 * rk[2][g];

    // xz = v0.xyz ; xr = v0.w, v1.xy ; xh = v1.zw, v2.x
    const float z0 = sigmoid_f(v0.x + inner[0]);
    const float z1 = sigmoid_f(v0.y + inner[1]);
    const float z2 = sigmoid_f(v0.z + inner[2]);
    const float r0 = sigmoid_f(v0.w + inner[3]);
    const float r1 = sigmoid_f(v1.x + inner[4]);
    const float r2 = sigmoid_f(v1.y + inner[5]);
    const float t0 = tanh_f(v1.z + r0 * inner[6]);
    const float t1 = tanh_f(v1.w + r1 * inner[7]);
    const float t2 = tanh_f(v2.x + r2 * inner[8]);
    h0 = t0 + z0 * (h0 - t0);
    h1 = t1 + z1 * (h1 - t1);
    h2 = t2 + z2 * (h2 - t2);

    v0 = n0; v1 = n1; v2 = n2;
  }

  // dense (3 -> 10) + softmax
  float lg[10];
#pragma unroll
  for (int j = 0; j < 10; ++j)
    lg[j] = dense_b[j] + h0 * dense_w[j] + h1 * dense_w[10 + j] + h2 * dense_w[20 + j];
  float m = lg[0];
#pragma unroll
  for (int j = 1; j < 10; ++j) m = fmaxf(m, lg[j]);
  float e[10];
  float ssum = 0.0f;
#pragma unroll
  for (int j = 0; j < 10; ++j) {
    e[j] = fast_exp2(1.4426950408889634f * (lg[j] - m));
    ssum += e[j];
  }
  const float inv = fast_rcp(ssum);
#pragma unroll
  for (int j = 0; j < 10; ++j) out[(size_t)b * 10 + j] = e[j] * inv;
}

extern "C" void kernel_launch(void* const* d_in, const int* in_sizes, int n_in,
                              void* d_out, int out_size, void* d_ws, size_t ws_size,
                              hipStream_t stream) {
  const float* x      = (const float*)d_in[0];  // [4096,256,64]
  const float* kern   = (const float*)d_in[1];  // [64,9]
  const float* rkern  = (const float*)d_in[2];  // [3,9]
  const float* bias   = (const float*)d_in[3];  // [2,9]
  const float* dw     = (const float*)d_in[4];  // [3,10]
  const float* db     = (const float*)d_in[5];  // [10]
  float* out = (float*)d_out;
  float* xk  = (float*)d_ws;  // needs S*B*12*4 = 48 MiB of workspace

  dim3 g1(BB / 64, SS);
  proj_kernel<<<g1, 256, 0, stream>>>(x, kern, bias, xk);
  gru_kernel<<<BB / 64, 64, 0, stream>>>(xk, rkern, bias, dw, db, out);
}

// Round 2
// 151.127 us; speedup vs baseline: 1.2777x; 1.2777x over previous
//
#include <hip/hip_runtime.h>

// Problem constants (from reference setup_inputs)
#define BB 4096   // batch
#define SS 256    // sequence length
#define FF 64     // features
#define GG 9      // 3*U gate width
#define GP 12     // padded gate width for float4 alignment
#define DPF 8     // prefetch depth (steps) for the GRU scan

#define NEG_LOG2E -1.4426950408889634f
#define TWO_LOG2E  2.8853900817779268f

typedef float f2 __attribute__((ext_vector_type(2)));

#if __has_builtin(__builtin_amdgcn_exp2f)
__device__ __forceinline__ float fast_exp2(float x) { return __builtin_amdgcn_exp2f(x); }
#else
__device__ __forceinline__ float fast_exp2(float x) { return exp2f(x); }
#endif
#if __has_builtin(__builtin_amdgcn_rcpf)
__device__ __forceinline__ float fast_rcp(float x) { return __builtin_amdgcn_rcpf(x); }
#else
__device__ __forceinline__ float fast_rcp(float x) { return 1.0f / x; }
#endif

// gate g column scale: z,r gates (0..5) by -log2e, h gates (6..8) by 2*log2e.
// Then sigmoid(u) = rcp(1+exp2(arg)) and tanh(u) = 1 - 2*rcp(1+exp2(arg))
// directly on the pre-scaled accumulators (no per-step scaling muls).
__device__ __forceinline__ float gate_scale(int g) {
  return (g < 6) ? NEG_LOG2E : TWO_LOG2E;
}

// Phase 1: xk[s][b][g] = (x[b,s,:] @ kernel[:,g] + bias[0][g]) * gate_scale(g)
__global__ __launch_bounds__(256) void proj_kernel(
    const float* __restrict__ x,       // [B,S,F]
    const float* __restrict__ kernel,  // [F,9]
    const float* __restrict__ bias,    // [2,9]
    float* __restrict__ xk)            // [S,B,12]
{
  const int lane = threadIdx.x & 63;
  const int wave = threadIdx.x >> 6;
  const int sub  = lane & 15;  // feature-chunk id within row group
  const int rg   = lane >> 4;  // row (batch) within wave

  // kernel slice for features 4*sub .. 4*sub+3 -> registers (36 VGPRs), pre-scaled
  float kk[4][GG];
#pragma unroll
  for (int f = 0; f < 4; ++f)
#pragma unroll
    for (int g = 0; g < GG; ++g)
      kk[f][g] = kernel[(4 * sub + f) * GG + g] * gate_scale(g);

  float b0[GG];
#pragma unroll
  for (int g = 0; g < GG; ++g) b0[g] = bias[g] * gate_scale(g);

  const int s = blockIdx.y;             // time step
  const int bbase = blockIdx.x * 64;    // 64 batches per block (4 iters x 16)

#pragma unroll
  for (int it = 0; it < 4; ++it) {
    const int b = bbase + it * 16 + wave * 4 + rg;
    const float4 xv = *reinterpret_cast<const float4*>(
        x + ((size_t)b * SS + s) * FF + sub * 4);
    float a[GG];
#pragma unroll
    for (int g = 0; g < GG; ++g)
      a[g] = xv.x * kk[0][g] + xv.y * kk[1][g] + xv.z * kk[2][g] + xv.w * kk[3][g];
    // butterfly reduce over the 16-lane row group (masks 1,2,4,8 stay in-group)
#pragma unroll
    for (int off = 1; off < 16; off <<= 1)
#pragma unroll
      for (int g = 0; g < GG; ++g)
        a[g] += __shfl_xor(a[g], off, 64);

    if (sub == 0) {
      float* o = xk + ((size_t)s * BB + b) * GP;
      float4 w0 = make_float4(a[0] + b0[0], a[1] + b0[1], a[2] + b0[2], a[3] + b0[3]);
      float4 w1 = make_float4(a[4] + b0[4], a[5] + b0[5], a[6] + b0[6], a[7] + b0[7]);
      float4 w2 = make_float4(a[8] + b0[8], 0.0f, 0.0f, 0.0f);
      *reinterpret_cast<float4*>(o)     = w0;
      *reinterpret_cast<float4*>(o + 4) = w1;
      *reinterpret_cast<float4*>(o + 8) = w2;
    }
  }
}

struct GruW {
  f2 rk[3][4];   // recurrent weights, gate pairs (0,1)(2,3)(4,5)(6,7), pre-scaled
  float rk8[3];  // gate 8 column
  f2 rb[4];      // recurrent bias pairs, pre-scaled
  float rb8;
};

// One GRU step. v0=(g0..g3), v1=(g4..g7), v2.x=g8. z gates 0-2, r gates 3-5,
// h gates 6-8. All x/recurrent contributions pre-scaled per gate_scale().
__device__ __forceinline__ void gru_step(const GruW& w,
    const float4 v0, const float4 v1, const float4 v2,
    float& h0, float& h1, float& h2) {
  f2 i01 = w.rb[0], i23 = w.rb[1], i45 = w.rb[2], i67 = w.rb[3];
  float i8 = w.rb8;
  i01 = h0 * w.rk[0][0] + i01; i23 = h0 * w.rk[0][1] + i23;
  i45 = h0 * w.rk[0][2] + i45; i67 = h0 * w.rk[0][3] + i67;
  i8 = fmaf(h0, w.rk8[0], i8);
  i01 = h1 * w.rk[1][0] + i01; i23 = h1 * w.rk[1][1] + i23;
  i45 = h1 * w.rk[1][2] + i45; i67 = h1 * w.rk[1][3] + i67;
  i8 = fmaf(h1, w.rk8[1], i8);
  i01 = h2 * w.rk[2][0] + i01; i23 = h2 * w.rk[2][1] + i23;
  i45 = h2 * w.rk[2][2] + i45; i67 = h2 * w.rk[2][3] + i67;
  i8 = fmaf(h2, w.rk8[2], i8);

  const f2 a01 = (f2){v0.x, v0.y} + i01;  // z0, z1 args
  const f2 a23 = (f2){v0.z, v0.w} + i23;  // z2, r0 args
  const f2 a45 = (f2){v1.x, v1.y} + i45;  // r1, r2 args

  const float z0 = fast_rcp(1.0f + fast_exp2(a01.x));
  const float z1 = fast_rcp(1.0f + fast_exp2(a01.y));
  const float z2 = fast_rcp(1.0f + fast_exp2(a23.x));
  const float r0 = fast_rcp(1.0f + fast_exp2(a23.y));
  const float r1 = fast_rcp(1.0f + fast_exp2(a45.x));
  const float r2 = fast_rcp(1.0f + fast_exp2(a45.y));

  const f2 a67 = (f2){r0, r1} * i67 + (f2){v1.z, v1.w};  // h0, h1 args
  const float a8 = fmaf(r2, i8, v2.x);                    // h2 arg

  const float t0 = fmaf(-2.0f, fast_rcp(1.0f + fast_exp2(a67.x)), 1.0f);
  const float t1 = fmaf(-2.0f, fast_rcp(1.0f + fast_exp2(a67.y)), 1.0f);
  const float t2 = fmaf(-2.0f, fast_rcp(1.0f + fast_exp2(a8)), 1.0f);

  h0 = fmaf(z0, h0 - t0, t0);
  h1 = fmaf(z1, h1 - t1, t1);
  h2 = fmaf(z2, h2 - t2, t2);
}

// Phase 2: per-batch sequential GRU scan + dense + softmax.
// 64 waves total -> occupancy is irrelevant; burn VGPRs on a depth-8
// double-buffered register prefetch to hide L3/HBM latency.
__global__ __launch_bounds__(64, 1) void gru_kernel(
    const float* __restrict__ xk,          // [S,B,12] (pre-scaled)
    const float* __restrict__ rec_kernel,  // [3,9]
    const float* __restrict__ bias,        // [2,9]
    const float* __restrict__ dense_w,     // [3,10]
    const float* __restrict__ dense_b,     // [10]
    float* __restrict__ out)               // [B,10]
{
  const int b = blockIdx.x * 64 + threadIdx.x;

  GruW w;
#pragma unroll
  for (int u = 0; u < 3; ++u) {
#pragma unroll
    for (int p = 0; p < 4; ++p)
      w.rk[u][p] = (f2){rec_kernel[u * GG + 2 * p] * gate_scale(2 * p),
                        rec_kernel[u * GG + 2 * p + 1] * gate_scale(2 * p + 1)};
    w.rk8[u] = rec_kernel[u * GG + 8] * TWO_LOG2E;
  }
#pragma unroll
  for (int p = 0; p < 4; ++p)
    w.rb[p] = (f2){bias[GG + 2 * p] * gate_scale(2 * p),
                   bias[GG + 2 * p + 1] * gate_scale(2 * p + 1)};
  w.rb8 = bias[GG + 8] * TWO_LOG2E;

  float h0 = 0.0f, h1 = 0.0f, h2 = 0.0f;

  float4 A[DPF][3], Bf[DPF][3];  // named double buffers, statically indexed

  auto loadg = [&](float4 (&buf)[DPF][3], int sbase) {
#pragma unroll
    for (int i = 0; i < DPF; ++i) {
      const float4* p = reinterpret_cast<const float4*>(
          xk + ((size_t)(sbase + i) * BB + b) * GP);
      buf[i][0] = p[0]; buf[i][1] = p[1]; buf[i][2] = p[2];
    }
  };

  loadg(A, 0);
  for (int sg = 0; sg < SS; sg += 2 * DPF) {
    loadg(Bf, sg + DPF);  // steps sg+8 .. sg+15 (always in range)
#pragma unroll
    for (int i = 0; i < DPF; ++i) gru_step(w, A[i][0], A[i][1], A[i][2], h0, h1, h2);
    if (sg + 2 * DPF < SS) loadg(A, sg + 2 * DPF);  // steps sg+16 .. sg+23
#pragma unroll
    for (int i = 0; i < DPF; ++i) gru_step(w, Bf[i][0], Bf[i][1], Bf[i][2], h0, h1, h2);
  }

  // dense (3 -> 10) + softmax
  float lg[10];
#pragma unroll
  for (int j = 0; j < 10; ++j)
    lg[j] = dense_b[j] + h0 * dense_w[j] + h1 * dense_w[10 + j] + h2 * dense_w[20 + j];
  float m = lg[0];
#pragma unroll
  for (int j = 1; j < 10; ++j) m = fmaxf(m, lg[j]);
  float e[10];
  float ssum = 0.0f;
#pragma unroll
  for (int j = 0; j < 10; ++j) {
    e[j] = fast_exp2(1.4426950408889634f * (lg[j] - m));
    ssum += e[j];
  }
  const float inv = fast_rcp(ssum);
#pragma unroll
  for (int j = 0; j < 10; ++j) out[(size_t)b * 10 + j] = e[j] * inv;
}

extern "C" void kernel_launch(void* const* d_in, const int* in_sizes, int n_in,
                              void* d_out, int out_size, void* d_ws, size_t ws_size,
                              hipStream_t stream) {
  const float* x      = (const float*)d_in[0];  // [4096,256,64]
  const float* kern   = (const float*)d_in[1];  // [64,9]
  const float* rkern  = (const float*)d_in[2];  // [3,9]
  const float* bias   = (const float*)d_in[3];  // [2,9]
  const float* dw     = (const float*)d_in[4];  // [3,10]
  const float* db     = (const float*)d_in[5];  // [10]
  float* out = (float*)d_out;
  float* xk  = (float*)d_ws;  // S*B*12*4 = 48 MiB of workspace

  dim3 g1(BB / 64, SS);
  proj_kernel<<<g1, 256, 0, stream>>>(x, kern, bias, xk);
  gru_kernel<<<BB / 64, 64, 0, stream>>>(xk, rkern, bias, dw, db, out);
}

// Round 3
// 118.561 us; speedup vs baseline: 1.6287x; 1.2747x over previous
//
#include <hip/hip_runtime.h>

// Problem constants (from reference setup_inputs)
#define BB 4096   // batch
#define SS 256    // sequence length
#define FF 64     // features
#define GG 9      // 3*U gate width

#define NEG_LOG2E -1.4426950408889634f
#define TWO_LOG2E  2.8853900817779268f

#if __has_builtin(__builtin_amdgcn_exp2f)
__device__ __forceinline__ float fast_exp2(float x) { return __builtin_amdgcn_exp2f(x); }
#else
__device__ __forceinline__ float fast_exp2(float x) { return exp2f(x); }
#endif
#if __has_builtin(__builtin_amdgcn_rcpf)
__device__ __forceinline__ float fast_rcp(float x) { return __builtin_amdgcn_rcpf(x); }
#else
__device__ __forceinline__ float fast_rcp(float x) { return 1.0f / x; }
#endif

// Broadcast within each 4-lane quad via DPP quad_perm (VALU-speed, no LDS).
template <int CTRL>
__device__ __forceinline__ float dpp_quad(float v) {
  return __int_as_float(
      __builtin_amdgcn_mov_dpp(__float_as_int(v), CTRL, 0xF, 0xF, true));
}

// -----------------------------------------------------------------------------
// Phase 1: input projection, shuffle-free. One thread per (b, s) row.
//   xk2 layout: [S][B][4][4] floats. Slot u (u=0..2) holds the pre-scaled
//   x-side gate args for unit u: { xz_u*(-log2e), xr_u*(-log2e),
//   xh_u*(2log2e), 0 }. Slot 3 is zero padding (completes 64B per (s,b)).
// Block = 256 threads: 64 batches x 4 timesteps; within a wave: 16 b x 4 s.
// -----------------------------------------------------------------------------
__global__ __launch_bounds__(256) void proj_kernel(
    const float* __restrict__ x,       // [B,S,F]
    const float* __restrict__ kernel,  // [F,9]
    const float* __restrict__ bias,    // [2,9]
    float* __restrict__ xk2)           // [S,B,4,4]
{
  const int lane = threadIdx.x & 63;
  const int wv   = threadIdx.x >> 6;
  const int bl   = lane >> 2;   // 0..15
  const int sl   = lane & 3;    // 0..3
  const int b = blockIdx.x * 64 + wv * 16 + bl;
  const int s = blockIdx.y * 4 + sl;

  // Load the full 256B feature row into registers (16 coalesced-through-L1
  // dwordx4; each 64B line is consumed by 4 successive loads of this lane).
  const float4* xp = reinterpret_cast<const float4*>(x + ((size_t)b * SS + s) * FF);
  float xr[FF];
#pragma unroll
  for (int i = 0; i < 16; ++i) {
    const float4 v = xp[i];
    xr[4 * i] = v.x; xr[4 * i + 1] = v.y; xr[4 * i + 2] = v.z; xr[4 * i + 3] = v.w;
  }

  float acc[GG];
#pragma unroll
  for (int g = 0; g < GG; ++g) acc[g] = bias[g];

  // Weights are wave-uniform -> scalar (s_load) fetches on the SMEM pipe.
#pragma unroll
  for (int f = 0; f < FF; ++f)
#pragma unroll
    for (int g = 0; g < GG; ++g)
      acc[g] = fmaf(xr[f], kernel[f * GG + g], acc[g]);

  float4* o = reinterpret_cast<float4*>(xk2 + ((size_t)s * BB + b) * 16);
  o[0] = make_float4(acc[0] * NEG_LOG2E, acc[3] * NEG_LOG2E, acc[6] * TWO_LOG2E, 0.0f);
  o[1] = make_float4(acc[1] * NEG_LOG2E, acc[4] * NEG_LOG2E, acc[7] * TWO_LOG2E, 0.0f);
  o[2] = make_float4(acc[2] * NEG_LOG2E, acc[5] * NEG_LOG2E, acc[8] * TWO_LOG2E, 0.0f);
  o[3] = make_float4(0.0f, 0.0f, 0.0f, 0.0f);
}

// -----------------------------------------------------------------------------
// Phase 2: GRU scan, 4 lanes per chain (lanes u=0..2 active, lane 3 benign).
// Lane u owns gates {z_u, r_u, h_u}; h-state broadcast per step via DPP.
// 64-thread blocks (16 chains), 256 blocks -> 1 wave on each of 256 CUs.
// -----------------------------------------------------------------------------
__global__ __launch_bounds__(64, 1) void gru_kernel(
    const float* __restrict__ xk2,         // [S,B,4,4] pre-scaled
    const float* __restrict__ rec_kernel,  // [3,9]
    const float* __restrict__ bias,        // [2,9]
    const float* __restrict__ dense_w,     // [3,10]
    const float* __restrict__ dense_b,     // [10]
    float* __restrict__ out)               // [B,10]
{
  const int lane = threadIdx.x;         // 0..63
  const int u    = lane & 3;            // unit slot within quad
  const int uc   = (u < 3) ? u : 2;     // lane 3: duplicate unit 2 (benign)
  const int c    = blockIdx.x * 16 + (lane >> 2);  // chain (batch) id

  // Per-lane recurrent weights for gates uc, 3+uc, 6+uc (pre-scaled).
  float wz[3], wr[3], wh[3];
#pragma unroll
  for (int hh = 0; hh < 3; ++hh) {
    wz[hh] = rec_kernel[hh * GG + uc]     * NEG_LOG2E;
    wr[hh] = rec_kernel[hh * GG + 3 + uc] * NEG_LOG2E;
    wh[hh] = rec_kernel[hh * GG + 6 + uc] * TWO_LOG2E;
  }
  const float rbz = bias[GG + uc]     * NEG_LOG2E;
  const float rbr = bias[GG + 3 + uc] * NEG_LOG2E;
  const float rbh = bias[GG + 6 + uc] * TWO_LOG2E;

  float h0 = 0.0f, h1 = 0.0f, h2 = 0.0f;

  // Per-step source: one float4 per lane, wave reads contiguous 1KB.
  const float4* base = reinterpret_cast<const float4*>(xk2) + ((size_t)c * 4 + u);
  const size_t pitch = (size_t)BB * 4;  // float4s per timestep

  float4 A[8], Bf[8];  // named double buffers, statically indexed
  auto loadg = [&](float4 (&buf)[8], int sbase) {
#pragma unroll
    for (int i = 0; i < 8; ++i) buf[i] = base[(size_t)(sbase + i) * pitch];
  };

  auto step = [&](const float4 v) {
    const float iz = fmaf(h2, wz[2], fmaf(h1, wz[1], fmaf(h0, wz[0], rbz)));
    const float ir = fmaf(h2, wr[2], fmaf(h1, wr[1], fmaf(h0, wr[0], rbr)));
    const float ih = fmaf(h2, wh[2], fmaf(h1, wh[1], fmaf(h0, wh[0], rbh)));
    const float z = fast_rcp(1.0f + fast_exp2(v.x + iz));
    const float r = fast_rcp(1.0f + fast_exp2(v.y + ir));
    const float t = fmaf(-2.0f, fast_rcp(1.0f + fast_exp2(fmaf(r, ih, v.z))), 1.0f);
    const float hsel = (u == 0) ? h0 : ((u == 1) ? h1 : h2);
    const float hn = fmaf(z, hsel - t, t);
    h0 = dpp_quad<0x00>(hn);  // quad_perm [0,0,0,0]
    h1 = dpp_quad<0x55>(hn);  // quad_perm [1,1,1,1]
    h2 = dpp_quad<0xAA>(hn);  // quad_perm [2,2,2,2]
  };

  loadg(A, 0);
  for (int sg = 0; sg < SS; sg += 16) {
    loadg(Bf, sg + 8);
#pragma unroll
    for (int i = 0; i < 8; ++i) step(A[i]);
    if (sg + 16 < SS) loadg(A, sg + 16);
#pragma unroll
    for (int i = 0; i < 8; ++i) step(Bf[i]);
  }

  // Dense (3 -> 10) + softmax. h0..h2 are broadcast, all lanes compute all
  // logits; lanes split the 10 stores (j = u, u+4, u+8).
  float lg[10];
#pragma unroll
  for (int j = 0; j < 10; ++j)
    lg[j] = dense_b[j] + h0 * dense_w[j] + h1 * dense_w[10 + j] + h2 * dense_w[20 + j];
  float m = lg[0];
#pragma unroll
  for (int j = 1; j < 10; ++j) m = fmaxf(m, lg[j]);
  float e[10];
  float ssum = 0.0f;
#pragma unroll
  for (int j = 0; j < 10; ++j) {
    e[j] = fast_exp2(1.4426950408889634f * (lg[j] - m));
    ssum += e[j];
  }
  const float inv = fast_rcp(ssum);
#pragma unroll
  for (int j = u; j < 10; j += 4) out[(size_t)c * 10 + j] = e[j] * inv;
}

extern "C" void kernel_launch(void* const* d_in, const int* in_sizes, int n_in,
                              void* d_out, int out_size, void* d_ws, size_t ws_size,
                              hipStream_t stream) {
  const float* x      = (const float*)d_in[0];  // [4096,256,64]
  const float* kern   = (const float*)d_in[1];  // [64,9]
  const float* rkern  = (const float*)d_in[2];  // [3,9]
  const float* bias   = (const float*)d_in[3];  // [2,9]
  const float* dw     = (const float*)d_in[4];  // [3,10]
  const float* db     = (const float*)d_in[5];  // [10]
  float* out = (float*)d_out;
  float* xk2 = (float*)d_ws;  // S*B*16*4 = 64 MiB of workspace

  dim3 g1(BB / 64, SS / 4);
  proj_kernel<<<g1, 256, 0, stream>>>(x, kern, bias, xk2);
  gru_kernel<<<BB / 16, 64, 0, stream>>>(xk2, rkern, bias, dw, db, out);
}

// Round 4
// 112.531 us; speedup vs baseline: 1.7160x; 1.0536x over previous
//
#include <hip/hip_runtime.h>

// Problem constants (from reference setup_inputs)
#define BB 4096   // batch
#define SS 256    // sequence length
#define FF 64     // features
#define GG 9      // 3*U gate width
#define TR 128    // rows per proj block

#define NEG_LOG2E -1.4426950408889634f
#define TWO_LOG2E  2.8853900817779268f

typedef float f2 __attribute__((ext_vector_type(2)));

#if __has_builtin(__builtin_amdgcn_exp2f)
__device__ __forceinline__ float fast_exp2(float x) { return __builtin_amdgcn_exp2f(x); }
#else
__device__ __forceinline__ float fast_exp2(float x) { return exp2f(x); }
#endif
#if __has_builtin(__builtin_amdgcn_rcpf)
__device__ __forceinline__ float fast_rcp(float x) { return __builtin_amdgcn_rcpf(x); }
#else
__device__ __forceinline__ float fast_rcp(float x) { return 1.0f / x; }
#endif

// Broadcast within each 4-lane quad via DPP quad_perm (VALU-speed, no LDS).
template <int CTRL>
__device__ __forceinline__ float dpp_quad(float v) {
  return __int_as_float(
      __builtin_amdgcn_mov_dpp(__float_as_int(v), CTRL, 0xF, 0xF, true));
}

// -----------------------------------------------------------------------------
// Phase 1: input projection. Coalesced global reads -> LDS transpose ->
// thread-per-row FMA loop (weights via uniform s_loads, x via conflict-free
// ds_read_b32). Gate scaling applied in the epilogue.
//   xk2 layout: [S][B][4][4] floats; slot u = { xz_u*-log2e, xr_u*-log2e,
//   xh_u*2log2e, 0 }; slot 3 zero. One 64B line per (s,b).
// -----------------------------------------------------------------------------
__global__ __launch_bounds__(128) void proj_kernel(
    const float* __restrict__ x,     // [B,S,F] = [rows 1M][64]
    const float* __restrict__ kw,    // [F,9]
    const float* __restrict__ bias,  // [2,9]
    float* __restrict__ xk2)         // [S,B,4,4]
{
  __shared__ float xT[FF][TR + 1];   // transposed tile, padded: 33 KB
  const int t = threadIdx.x;         // 0..127
  const size_t row0 = (size_t)blockIdx.x * TR;

  // Stage 128 rows x 256B, perfectly coalesced (wave = 1KB contiguous/instr).
  const float4* xp = reinterpret_cast<const float4*>(x + row0 * FF);
  float4 v[16];
#pragma unroll
  for (int k = 0; k < 16; ++k) v[k] = xp[k * TR + t];

  // Transpose into LDS: bank = (4*(t&15) + t/16 + const) % 32 -> conflict-free.
#pragma unroll
  for (int k = 0; k < 16; ++k) {
    const int j = k * TR + t;
    const int r = j >> 4;            // row within tile 0..127
    const int c4 = (j & 15) << 2;    // first feature of this float4
    xT[c4 + 0][r] = v[k].x;
    xT[c4 + 1][r] = v[k].y;
    xT[c4 + 2][r] = v[k].z;
    xT[c4 + 3][r] = v[k].w;
  }
  __syncthreads();

  // Thread t computes row (row0 + t): 9 dots of length 64.
  f2 a01 = {bias[0], bias[1]};
  f2 a23 = {bias[2], bias[3]};
  f2 a45 = {bias[4], bias[5]};
  f2 a67 = {bias[6], bias[7]};
  float a8 = bias[8];
#pragma unroll
  for (int f = 0; f < FF; ++f) {
    const float xf = xT[f][t];       // stride-1 lanes: no bank conflicts
    const f2 w01 = {kw[f * GG + 0], kw[f * GG + 1]};
    const f2 w23 = {kw[f * GG + 2], kw[f * GG + 3]};
    const f2 w45 = {kw[f * GG + 4], kw[f * GG + 5]};
    const f2 w67 = {kw[f * GG + 6], kw[f * GG + 7]};
    a01 = xf * w01 + a01;
    a23 = xf * w23 + a23;
    a45 = xf * w45 + a45;
    a67 = xf * w67 + a67;
    a8 = fmaf(xf, kw[f * GG + 8], a8);
  }

  // gates: z = g0..g2, r = g3..g5, h = g6..g8
  const size_t row = row0 + t;
  const int b = (int)(row >> 8);     // row / SS
  const int s = (int)(row & 255);    // row % SS
  float4* o = reinterpret_cast<float4*>(xk2 + ((size_t)s * BB + b) * 16);
  o[0] = make_float4(a01.x * NEG_LOG2E, a23.y * NEG_LOG2E, a67.x * TWO_LOG2E, 0.0f);
  o[1] = make_float4(a01.y * NEG_LOG2E, a45.x * NEG_LOG2E, a67.y * TWO_LOG2E, 0.0f);
  o[2] = make_float4(a23.x * NEG_LOG2E, a45.y * NEG_LOG2E, a8    * TWO_LOG2E, 0.0f);
  o[3] = make_float4(0.0f, 0.0f, 0.0f, 0.0f);
}

// -----------------------------------------------------------------------------
// Phase 2: GRU scan, 4 lanes per chain (lanes u=0..2 active, lane 3 benign).
// Lane u owns gates {z_u, r_u, h_u}; h broadcast per step via DPP quad_perm.
// 256 blocks x 1 wave -> one wave per CU; depth-8 double-buffered prefetch.
// -----------------------------------------------------------------------------
__global__ __launch_bounds__(64, 1) void gru_kernel(
    const float* __restrict__ xk2,         // [S,B,4,4] pre-scaled
    const float* __restrict__ rec_kernel,  // [3,9]
    const float* __restrict__ bias,        // [2,9]
    const float* __restrict__ dense_w,     // [3,10]
    const float* __restrict__ dense_b,     // [10]
    float* __restrict__ out)               // [B,10]
{
  const int lane = threadIdx.x;         // 0..63
  const int u    = lane & 3;            // unit slot within quad
  const int uc   = (u < 3) ? u : 2;     // lane 3: clamp weight indices
  const int c    = blockIdx.x * 16 + (lane >> 2);  // chain (batch) id

  float wz[3], wr[3], wh[3];
#pragma unroll
  for (int hh = 0; hh < 3; ++hh) {
    wz[hh] = rec_kernel[hh * GG + uc]     * NEG_LOG2E;
    wr[hh] = rec_kernel[hh * GG + 3 + uc] * NEG_LOG2E;
    wh[hh] = rec_kernel[hh * GG + 6 + uc] * TWO_LOG2E;
  }
  const float rbz = bias[GG + uc]     * NEG_LOG2E;
  const float rbr = bias[GG + 3 + uc] * NEG_LOG2E;
  const float rbh = bias[GG + 6 + uc] * TWO_LOG2E;

  float h0 = 0.0f, h1 = 0.0f, h2 = 0.0f;
  float hprev = 0.0f;  // this lane's own gate-u state (== h_u for u<3)

  const float4* base = reinterpret_cast<const float4*>(xk2) + ((size_t)c * 4 + u);
  const size_t pitch = (size_t)BB * 4;  // float4s per timestep

  float4 A[8], Bf[8];  // named double buffers, statically indexed
  auto loadg = [&](float4 (&buf)[8], int sbase) {
#pragma unroll
    for (int i = 0; i < 8; ++i) buf[i] = base[(size_t)(sbase + i) * pitch];
  };

  auto step = [&](const float4 v) {
    const float az = v.x + rbz;  // off the h critical path (v prefetched)
    const float ar = v.y + rbr;
    const float iz = fmaf(h2, wz[2], fmaf(h1, wz[1], fmaf(h0, wz[0], az)));
    const float ir = fmaf(h2, wr[2], fmaf(h1, wr[1], fmaf(h0, wr[0], ar)));
    const float ih = fmaf(h2, wh[2], fmaf(h1, wh[1], fmaf(h0, wh[0], rbh)));
    const float z = fast_rcp(1.0f + fast_exp2(iz));
    const float r = fast_rcp(1.0f + fast_exp2(ir));
    const float t = fmaf(-2.0f, fast_rcp(1.0f + fast_exp2(fmaf(r, ih, v.z))), 1.0f);
    const float hn = fmaf(z, hprev - t, t);
    hprev = hn;
    h0 = dpp_quad<0x00>(hn);  // quad_perm [0,0,0,0]
    h1 = dpp_quad<0x55>(hn);  // quad_perm [1,1,1,1]
    h2 = dpp_quad<0xAA>(hn);  // quad_perm [2,2,2,2]
  };

  loadg(A, 0);
  for (int sg = 0; sg < SS; sg += 16) {
    loadg(Bf, sg + 8);
#pragma unroll
    for (int i = 0; i < 8; ++i) step(A[i]);
    if (sg + 16 < SS) loadg(A, sg + 16);
#pragma unroll
    for (int i = 0; i < 8; ++i) step(Bf[i]);
  }

  // Dense (3 -> 10) + softmax; h0..h2 broadcast so all lanes agree.
  float lg[10];
#pragma unroll
  for (int j = 0; j < 10; ++j)
    lg[j] = dense_b[j] + h0 * dense_w[j] + h1 * dense_w[10 + j] + h2 * dense_w[20 + j];
  float m = lg[0];
#pragma unroll
  for (int j = 1; j < 10; ++j) m = fmaxf(m, lg[j]);
  float e[10];
  float ssum = 0.0f;
#pragma unroll
  for (int j = 0; j < 10; ++j) {
    e[j] = fast_exp2(1.4426950408889634f * (lg[j] - m));
    ssum += e[j];
  }
  const float inv = fast_rcp(ssum);
#pragma unroll
  for (int j = u; j < 10; j += 4) out[(size_t)c * 10 + j] = e[j] * inv;
}

extern "C" void kernel_launch(void* const* d_in, const int* in_sizes, int n_in,
                              void* d_out, int out_size, void* d_ws, size_t ws_size,
                              hipStream_t stream) {
  const float* x      = (const float*)d_in[0];  // [4096,256,64]
  const float* kern   = (const float*)d_in[1];  // [64,9]
  const float* rkern  = (const float*)d_in[2];  // [3,9]
  const float* bias   = (const float*)d_in[3];  // [2,9]
  const float* dw     = (const float*)d_in[4];  // [3,10]
  const float* db     = (const float*)d_in[5];  // [10]
  float* out = (float*)d_out;
  float* xk2 = (float*)d_ws;  // S*B*16*4 = 64 MiB of workspace

  const int nrows = BB * SS;                    // 1,048,576 rows
  proj_kernel<<<nrows / TR, TR, 0, stream>>>(x, kern, bias, xk2);
  gru_kernel<<<BB / 16, 64, 0, stream>>>(xk2, rkern, bias, dw, db, out);
}

// Round 5
// 90.763 us; speedup vs baseline: 2.1275x; 1.2398x over previous
//
#include <hip/hip_runtime.h>

// Problem constants (from reference setup_inputs)
#define BB 4096   // batch
#define SS 256    // sequence length
#define FF 64     // features
#define GG 9      // 3*U gate width

#define NEG_LOG2E -1.4426950408889634f
#define TWO_LOG2E  2.8853900817779268f

typedef float f2 __attribute__((ext_vector_type(2)));

#if __has_builtin(__builtin_amdgcn_exp2f)
__device__ __forceinline__ float fast_exp2(float x) { return __builtin_amdgcn_exp2f(x); }
#else
__device__ __forceinline__ float fast_exp2(float x) { return exp2f(x); }
#endif
#if __has_builtin(__builtin_amdgcn_rcpf)
__device__ __forceinline__ float fast_rcp(float x) { return __builtin_amdgcn_rcpf(x); }
#else
__device__ __forceinline__ float fast_rcp(float x) { return 1.0f / x; }
#endif

// Quad-lane DPP helper (verified absmax-0 in R3/R4).
template <int CTRL>
__device__ __forceinline__ float dpp_quad(float v) {
  return __int_as_float(
      __builtin_amdgcn_mov_dpp(__float_as_int(v), CTRL, 0xF, 0xF, true));
}

// -----------------------------------------------------------------------------
// Fully fused GRU: input projection + scan + dense + softmax in ONE kernel.
// 256 blocks x 1 wave (one per CU). 16 chains/block, 4 lanes/chain.
// Feature split: lane (c,u) owns features {j*16 + u*4 + e : j,e in 0..3} of
// chain c, with the matching pre-scaled kernel columns in VGPRs (144 regs).
// Per step: 4 coalesced dwordx4 loads (64B contiguous per chain per instr),
// 80 packed FMAs, 2-stage quad_perm butterfly reduce, gate math on lanes
// u=0..2, h broadcast via quad_perm. Depth-4 register ring hides HBM latency.
// Gate scaling folded into weights: gates 0-5 by -log2e, gates 6-8 by 2log2e.
// -----------------------------------------------------------------------------
__global__ __launch_bounds__(64, 1) void fused_gru_kernel(
    const float* __restrict__ x,           // [B,S,F]
    const float* __restrict__ kernel_w,    // [F,9]
    const float* __restrict__ rec_kernel,  // [3,9]
    const float* __restrict__ bias,        // [2,9]
    const float* __restrict__ dense_w,     // [3,10]
    const float* __restrict__ dense_b,     // [10]
    float* __restrict__ out)               // [B,10]
{
  const int lane = threadIdx.x;        // 0..63
  const int u    = lane & 3;           // quad slot (feature sub-slice / unit)
  const int uc   = (u < 3) ? u : 2;    // lane 3: clamp unit role (benign)
  const int c    = blockIdx.x * 16 + (lane >> 2);  // chain (batch) id

  // ---- input-projection weights for this lane's 16 features (pre-scaled)
  f2 w01[16], w23[16], w45[16], w67[16];
  float w8[16];
#pragma unroll
  for (int j = 0; j < 4; ++j)
#pragma unroll
    for (int e = 0; e < 4; ++e) {
      const int fi = j * 16 + u * 4 + e;   // feature index
      const int sl = j * 4 + e;            // register slot
      const float* kw = kernel_w + fi * GG;
      w01[sl] = (f2){kw[0] * NEG_LOG2E, kw[1] * NEG_LOG2E};
      w23[sl] = (f2){kw[2] * NEG_LOG2E, kw[3] * NEG_LOG2E};
      w45[sl] = (f2){kw[4] * NEG_LOG2E, kw[5] * NEG_LOG2E};
      w67[sl] = (f2){kw[6] * TWO_LOG2E, kw[7] * TWO_LOG2E};
      w8[sl]  = kw[8] * TWO_LOG2E;
    }

  // input bias, pre-scaled AND quartered (each quad lane adds it once; the
  // 4-lane reduce sums it back to exactly 1x since 0.25 is a power of two).
  const f2 b01q = {bias[0] * NEG_LOG2E * 0.25f, bias[1] * NEG_LOG2E * 0.25f};
  const f2 b23q = {bias[2] * NEG_LOG2E * 0.25f, bias[3] * NEG_LOG2E * 0.25f};
  const f2 b45q = {bias[4] * NEG_LOG2E * 0.25f, bias[5] * NEG_LOG2E * 0.25f};
  const f2 b67q = {bias[6] * TWO_LOG2E * 0.25f, bias[7] * TWO_LOG2E * 0.25f};
  const float b8q = bias[8] * TWO_LOG2E * 0.25f;

  // recurrent weights/bias for this lane's unit (pre-scaled)
  float wz[3], wr[3], wh[3];
#pragma unroll
  for (int hh = 0; hh < 3; ++hh) {
    wz[hh] = rec_kernel[hh * GG + uc]     * NEG_LOG2E;
    wr[hh] = rec_kernel[hh * GG + 3 + uc] * NEG_LOG2E;
    wh[hh] = rec_kernel[hh * GG + 6 + uc] * TWO_LOG2E;
  }
  const float rbz = bias[GG + uc]     * NEG_LOG2E;
  const float rbr = bias[GG + 3 + uc] * NEG_LOG2E;
  const float rbh = bias[GG + 6 + uc] * TWO_LOG2E;

  float h0 = 0.0f, h1 = 0.0f, h2 = 0.0f, hprev = 0.0f;

  // per-lane x pointer: row (c, s) has 16 float4s; this lane reads col j*4+u.
  const float4* pc = reinterpret_cast<const float4*>(x) + (size_t)c * SS * 16 + u;

  float4 X0[4], X1[4], X2[4], X3[4];  // 4-step register ring, static indexing
  auto loads = [&](float4 (&Xs)[4], int s) {
#pragma unroll
    for (int j = 0; j < 4; ++j) Xs[j] = pc[(size_t)s * 16 + j * 4];
  };

  auto step = [&](const float4 (&Xs)[4]) {
    f2 a01 = b01q, a23 = b23q, a45 = b45q, a67 = b67q;
    float a8 = b8q;
#pragma unroll
    for (int j = 0; j < 4; ++j) {
      const float4 v = Xs[j];
      const int sl = j * 4;
      a01 = v.x * w01[sl+0] + a01; a23 = v.x * w23[sl+0] + a23;
      a45 = v.x * w45[sl+0] + a45; a67 = v.x * w67[sl+0] + a67;
      a8 = fmaf(v.x, w8[sl+0], a8);
      a01 = v.y * w01[sl+1] + a01; a23 = v.y * w23[sl+1] + a23;
      a45 = v.y * w45[sl+1] + a45; a67 = v.y * w67[sl+1] + a67;
      a8 = fmaf(v.y, w8[sl+1], a8);
      a01 = v.z * w01[sl+2] + a01; a23 = v.z * w23[sl+2] + a23;
      a45 = v.z * w45[sl+2] + a45; a67 = v.z * w67[sl+2] + a67;
      a8 = fmaf(v.z, w8[sl+2], a8);
      a01 = v.w * w01[sl+3] + a01; a23 = v.w * w23[sl+3] + a23;
      a45 = v.w * w45[sl+3] + a45; a67 = v.w * w67[sl+3] + a67;
      a8 = fmaf(v.w, w8[sl+3], a8);
    }
    // 2-stage butterfly over the quad -> every lane holds all 9 full dots
    float s0 = a01.x, s1 = a01.y, s2 = a23.x, s3 = a23.y, s4 = a45.x,
          s5 = a45.y, s6 = a67.x, s7 = a67.y, s8 = a8;
    s0 += dpp_quad<0xB1>(s0); s1 += dpp_quad<0xB1>(s1); s2 += dpp_quad<0xB1>(s2);
    s3 += dpp_quad<0xB1>(s3); s4 += dpp_quad<0xB1>(s4); s5 += dpp_quad<0xB1>(s5);
    s6 += dpp_quad<0xB1>(s6); s7 += dpp_quad<0xB1>(s7); s8 += dpp_quad<0xB1>(s8);
    s0 += dpp_quad<0x4E>(s0); s1 += dpp_quad<0x4E>(s1); s2 += dpp_quad<0x4E>(s2);
    s3 += dpp_quad<0x4E>(s3); s4 += dpp_quad<0x4E>(s4); s5 += dpp_quad<0x4E>(s5);
    s6 += dpp_quad<0x4E>(s6); s7 += dpp_quad<0x4E>(s7); s8 += dpp_quad<0x4E>(s8);
    // this lane's gates (z_u, r_u, h_u); lane 3 duplicates unit 2 (unused)
    const float sz = (u == 0) ? s0 : ((u == 1) ? s1 : s2);
    const float sr = (u == 0) ? s3 : ((u == 1) ? s4 : s5);
    const float sh = (u == 0) ? s6 : ((u == 1) ? s7 : s8);
    const float iz = fmaf(h2, wz[2], fmaf(h1, wz[1], fmaf(h0, wz[0], sz + rbz)));
    const float ir = fmaf(h2, wr[2], fmaf(h1, wr[1], fmaf(h0, wr[0], sr + rbr)));
    const float ih = fmaf(h2, wh[2], fmaf(h1, wh[1], fmaf(h0, wh[0], rbh)));
    const float z = fast_rcp(1.0f + fast_exp2(iz));
    const float r = fast_rcp(1.0f + fast_exp2(ir));
    const float t = fmaf(-2.0f, fast_rcp(1.0f + fast_exp2(fmaf(r, ih, sh))), 1.0f);
    const float hn = fmaf(z, hprev - t, t);
    hprev = hn;
    h0 = dpp_quad<0x00>(hn);
    h1 = dpp_quad<0x55>(hn);
    h2 = dpp_quad<0xAA>(hn);
  };

  loads(X0, 0); loads(X1, 1); loads(X2, 2); loads(X3, 3);
  for (int sg = 0; sg < SS; sg += 4) {
    step(X0); { int sn = sg + 4; if (sn >= SS) sn = SS - 4; loads(X0, sn); }
    step(X1); { int sn = sg + 5; if (sn >= SS) sn = SS - 4; loads(X1, sn); }
    step(X2); { int sn = sg + 6; if (sn >= SS) sn = SS - 4; loads(X2, sn); }
    step(X3); { int sn = sg + 7; if (sn >= SS) sn = SS - 4; loads(X3, sn); }
  }

  // Dense (3 -> 10) + softmax; h0..h2 broadcast so all quad lanes agree.
  float lg[10];
#pragma unroll
  for (int j = 0; j < 10; ++j)
    lg[j] = dense_b[j] + h0 * dense_w[j] + h1 * dense_w[10 + j] + h2 * dense_w[20 + j];
  float m = lg[0];
#pragma unroll
  for (int j = 1; j < 10; ++j) m = fmaxf(m, lg[j]);
  float e[10];
  float ssum = 0.0f;
#pragma unroll
  for (int j = 0; j < 10; ++j) {
    e[j] = fast_exp2(1.4426950408889634f * (lg[j] - m));
    ssum += e[j];
  }
  const float inv = fast_rcp(ssum);
#pragma unroll
  for (int j = u; j < 10; j += 4) out[(size_t)c * 10 + j] = e[j] * inv;
}

extern "C" void kernel_launch(void* const* d_in, const int* in_sizes, int n_in,
                              void* d_out, int out_size, void* d_ws, size_t ws_size,
                              hipStream_t stream) {
  const float* x      = (const float*)d_in[0];  // [4096,256,64]
  const float* kern   = (const float*)d_in[1];  // [64,9]
  const float* rkern  = (const float*)d_in[2];  // [3,9]
  const float* bias   = (const float*)d_in[3];  // [2,9]
  const float* dw     = (const float*)d_in[4];  // [3,10]
  const float* db     = (const float*)d_in[5];  // [10]
  float* out = (float*)d_out;

  fused_gru_kernel<<<BB / 16, 64, 0, stream>>>(x, kern, rkern, bias, dw, db, out);
}